// Round 2
// baseline (1594.327 us; speedup 1.0000x reference)
//
#include <hip/hip_runtime.h>

#define N_ 200000
#define E_ 6400000
#define F_ 128
#define H_ 16
#define C_ 10
#define B_ 512

#define BSH   8                      // bucket shift: 256 nodes/bucket
#define NBUCK 782                    // ceil(N/256)
#define NT    800                    // partition tiles
#define EPT   8000                   // edges per tile (NT*EPT == E_)

// ---------- 1. per-tile bucket histogram ----------
__global__ __launch_bounds__(256) void k_count(const int* __restrict__ col, int* __restrict__ cnt_mat) {
    __shared__ int hist[NBUCK];
    int tid = threadIdx.x, tile = blockIdx.x;
    for (int b = tid; b < NBUCK; b += 256) hist[b] = 0;
    __syncthreads();
    const int* c = col + (size_t)tile * EPT;
    for (int i = tid; i < EPT; i += 256) atomicAdd(&hist[c[i] >> BSH], 1);
    __syncthreads();
    for (int b = tid; b < NBUCK; b += 256) cnt_mat[(size_t)tile * NBUCK + b] = hist[b];
}

// ---------- 2. per-bucket column scan (exclusive, in place) + totals ----------
__global__ __launch_bounds__(256) void k_scan_col(int* __restrict__ cnt_mat, int* __restrict__ bucketTotal) {
    __shared__ int s[256];
    int b = blockIdx.x, t = threadIdx.x;
    int v[4];
    int seg = 0;
#pragma unroll
    for (int j = 0; j < 4; ++j) {
        int idx = 4 * t + j;
        v[j] = (idx < NT) ? cnt_mat[(size_t)idx * NBUCK + b] : 0;
        seg += v[j];
    }
    s[t] = seg;
    __syncthreads();
    for (int off = 1; off < 256; off <<= 1) {
        int tmp = (t >= off) ? s[t - off] : 0;
        __syncthreads();
        s[t] += tmp;
        __syncthreads();
    }
    if (t == 255) bucketTotal[b] = s[255];
    int running = s[t] - seg;          // exclusive base for this thread's segment
#pragma unroll
    for (int j = 0; j < 4; ++j) {
        int idx = 4 * t + j;
        if (idx < NT) {
            int old = v[j];
            cnt_mat[(size_t)idx * NBUCK + b] = running;
            running += old;
        }
    }
}

// ---------- 3. scan bucket totals -> bucketStart[NBUCK+1] ----------
__global__ __launch_bounds__(1024) void k_scan_top(const int* __restrict__ bucketTotal, int* __restrict__ bucketStart) {
    __shared__ int s[1024];
    int t = threadIdx.x;
    int val = (t < NBUCK) ? bucketTotal[t] : 0;
    s[t] = val;
    __syncthreads();
    for (int off = 1; off < 1024; off <<= 1) {
        int tmp = (t >= off) ? s[t - off] : 0;
        __syncthreads();
        s[t] += tmp;
        __syncthreads();
    }
    if (t < NBUCK) bucketStart[t] = s[t] - val;
    if (t == NBUCK - 1) bucketStart[NBUCK] = s[t];   // == E_
}

// ---------- 4. add bucket starts to chunk bases ----------
__global__ __launch_bounds__(256) void k_addbase(int* __restrict__ cnt_mat, const int* __restrict__ bucketStart) {
    int i = blockIdx.x * 256 + threadIdx.x;
    if (i < NT * NBUCK) cnt_mat[i] += bucketStart[i % NBUCK];
}

// ---------- 5. partition edges into buckets (packed: row | c_local<<24) ----------
__global__ __launch_bounds__(256) void k_part(const int* __restrict__ row, const int* __restrict__ col,
                                              const int* __restrict__ cnt_mat, unsigned int* __restrict__ edges_part) {
    __shared__ int cur[NBUCK];
    int tid = threadIdx.x, tile = blockIdx.x;
    for (int b = tid; b < NBUCK; b += 256) cur[b] = cnt_mat[(size_t)tile * NBUCK + b];
    __syncthreads();
    const int* r = row + (size_t)tile * EPT;
    const int* c = col + (size_t)tile * EPT;
    for (int i = tid; i < EPT; i += 256) {
        int cc = c[i];
        int b = cc >> BSH;
        int p = atomicAdd(&cur[b], 1);
        edges_part[p] = (unsigned int)r[i] | ((unsigned int)(cc & 255) << 24);
    }
}

// ---------- 6. per-bucket degree -> dis = rsqrt(1+deg) ----------
__global__ __launch_bounds__(256) void k_degB(const unsigned int* __restrict__ edges_part,
                                              const int* __restrict__ bucketStart, float* __restrict__ dis) {
    __shared__ int cnt[256];
    int b = blockIdx.x, tid = threadIdx.x;
    cnt[tid] = 0;
    __syncthreads();
    int s = bucketStart[b], e = bucketStart[b + 1];
    for (int i = s + tid; i < e; i += 256) atomicAdd(&cnt[edges_part[i] >> 24], 1);
    __syncthreads();
    int n = (b << BSH) + tid;
    if (n < N_) dis[n] = rsqrtf(1.0f + (float)cnt[tid]);
}

// ---------- 7. GEMM1: hws[n][h] = dis[n] * (x[n] @ W1)[h] ----------
__global__ __launch_bounds__(256) void k_gemm1s(const float* __restrict__ x, const float* __restrict__ W1,
                                                const float* __restrict__ dis, float* __restrict__ hws) {
    __shared__ float w[F_ * H_];
    for (int i = threadIdx.x; i < F_ * H_; i += 256) w[i] = W1[i];
    __syncthreads();
    int n = blockIdx.x * 256 + threadIdx.x;
    if (n >= N_) return;
    float acc[H_];
#pragma unroll
    for (int h = 0; h < H_; ++h) acc[h] = 0.f;
    const float4* xr = reinterpret_cast<const float4*>(x + (size_t)n * F_);
#pragma unroll 4
    for (int k4 = 0; k4 < F_ / 4; ++k4) {
        float4 xv = xr[k4];
        int k = k4 * 4;
#pragma unroll
        for (int h = 0; h < H_; ++h) {
            acc[h] += xv.x * w[(k + 0) * H_ + h] + xv.y * w[(k + 1) * H_ + h]
                    + xv.z * w[(k + 2) * H_ + h] + xv.w * w[(k + 3) * H_ + h];
        }
    }
    float dn = dis[n];
    float* o = hws + (size_t)n * H_;
#pragma unroll
    for (int h = 0; h < H_; h += 4)
        *(float4*)(o + h) = make_float4(acc[h] * dn, acc[h + 1] * dn, acc[h + 2] * dn, acc[h + 3] * dn);
}

// ---------- 9. GEMM2: hws[n][h] = dis[n] * (hin[n] @ W2)[h] ----------
__global__ __launch_bounds__(256) void k_gemm2s(const float* __restrict__ hin, const float* __restrict__ W2,
                                                const float* __restrict__ dis, float* __restrict__ hws) {
    __shared__ float w[H_ * H_];
    if (threadIdx.x < H_ * H_) w[threadIdx.x] = W2[threadIdx.x];
    __syncthreads();
    int n = blockIdx.x * 256 + threadIdx.x;
    if (n >= N_) return;
    float hv[H_];
    const float4* hr = reinterpret_cast<const float4*>(hin + (size_t)n * H_);
#pragma unroll
    for (int q = 0; q < 4; ++q) {
        float4 v = hr[q];
        hv[q * 4 + 0] = v.x; hv[q * 4 + 1] = v.y; hv[q * 4 + 2] = v.z; hv[q * 4 + 3] = v.w;
    }
    float acc[H_];
#pragma unroll
    for (int h = 0; h < H_; ++h) acc[h] = 0.f;
#pragma unroll
    for (int k = 0; k < H_; ++k)
#pragma unroll
        for (int h = 0; h < H_; ++h) acc[h] += hv[k] * w[k * H_ + h];
    float dn = dis[n];
    float* o = hws + (size_t)n * H_;
#pragma unroll
    for (int h = 0; h < H_; h += 4)
        *(float4*)(o + h) = make_float4(acc[h] * dn, acc[h + 1] * dn, acc[h + 2] * dn, acc[h + 3] * dn);
}

// ---------- 8/10. fused per-bucket aggregation ----------
// out[n][h] = dis[n]*(sum_{edges->n} hws[r][h] + hws[n][h]) + bias[h]   (+relu)
template <int RELU>
__global__ __launch_bounds__(256) void k_agg(const float* __restrict__ hws, const unsigned int* __restrict__ edges_part,
                                             const int* __restrict__ bucketStart, const float* __restrict__ dis,
                                             const float* __restrict__ bias, float* __restrict__ outp) {
    __shared__ float acc[256 * H_];      // 16 KB
    __shared__ unsigned int est[256];    // 1 KB
    int b = blockIdx.x, tid = threadIdx.x;
    for (int i = tid; i < 256 * H_; i += 256) acc[i] = 0.f;
    __syncthreads();
    int s = bucketStart[b], e = bucketStart[b + 1];
    int esub = tid >> 4, h = tid & 15;
    for (int chunk = s; chunk < e; chunk += 256) {
        int m = min(256, e - chunk);
        if (tid < m) est[tid] = edges_part[chunk + tid];
        __syncthreads();
        if (m == 256) {
#pragma unroll 4
            for (int k = esub; k < 256; k += 16) {
                unsigned int pk = est[k];
                int r = pk & 0x00FFFFFFu;
                int cl = pk >> 24;
                float v = hws[(size_t)r * H_ + h];
                atomicAdd(&acc[(cl << 4) + h], v);
            }
        } else {
            for (int k = esub; k < m; k += 16) {
                unsigned int pk = est[k];
                int r = pk & 0x00FFFFFFu;
                int cl = pk >> 24;
                float v = hws[(size_t)r * H_ + h];
                atomicAdd(&acc[(cl << 4) + h], v);
            }
        }
        __syncthreads();
    }
    float bh = bias[h];
#pragma unroll
    for (int it = 0; it < 16; ++it) {
        int nsub = (it << 4) + esub;
        int n = (b << BSH) + nsub;
        if (n < N_) {
            float dn = dis[n];
            float v = dn * (acc[(nsub << 4) + h] + hws[(size_t)n * H_ + h]) + bh;
            if (RELU) v = fmaxf(v, 0.f);
            outp[(size_t)n * H_ + h] = v;
        }
    }
}

// ---------- 11. pool + fc ----------
__global__ __launch_bounds__(64) void k_pool_fc(const float* __restrict__ h2, const int* __restrict__ batch,
                                                const float* __restrict__ Wfc, const float* __restrict__ bfc,
                                                float* __restrict__ out) {
    int b = blockIdx.x;
    int lo = 0, hi = N_;
    while (lo < hi) { int m = (lo + hi) >> 1; if (batch[m] < b) lo = m + 1; else hi = m; }
    int start = lo;
    lo = start; hi = N_;
    while (lo < hi) { int m = (lo + hi) >> 1; if (batch[m] < b + 1) lo = m + 1; else hi = m; }
    int end = lo;

    int t = threadIdx.x;
    int h = t & 15, q = t >> 4;
    float acc = 0.f;
    for (int n = start + q; n < end; n += 4) acc += h2[(size_t)n * H_ + h];
    acc += __shfl_xor(acc, 16);
    acc += __shfl_xor(acc, 32);

    __shared__ float pooled[H_];
    float cntf = fmaxf((float)(end - start), 1.0f);
    if (t < H_) pooled[t] = acc / cntf;
    __syncthreads();
    if (t < C_) {
        float o = bfc[t];
#pragma unroll
        for (int hh = 0; hh < H_; ++hh) o += pooled[hh] * Wfc[hh * C_ + t];
        out[b * C_ + t] = o;
    }
}

extern "C" void kernel_launch(void* const* d_in, const int* in_sizes, int n_in,
                              void* d_out, int out_size, void* d_ws, size_t ws_size,
                              hipStream_t stream) {
    const float* x    = (const float*)d_in[0];
    const int*   ei   = (const int*)d_in[1];
    const int*   batch= (const int*)d_in[2];
    const float* W1   = (const float*)d_in[3];
    const float* b1   = (const float*)d_in[4];
    const float* W2   = (const float*)d_in[5];
    const float* b2   = (const float*)d_in[6];
    const float* Wfc  = (const float*)d_in[7];
    const float* bfc  = (const float*)d_in[8];
    float* out = (float*)d_out;

    const int* row = ei;
    const int* col = ei + E_;

    size_t off = 0;
    auto alloc = [&](size_t bytes) -> void* {
        void* p = (char*)d_ws + off;
        off += (bytes + 255) & ~(size_t)255;
        return p;
    };
    int*          cnt_mat     = (int*)         alloc((size_t)NT * NBUCK * 4);   // 2.5 MB
    int*          bucketTotal = (int*)         alloc((size_t)NBUCK * 4);
    int*          bucketStart = (int*)         alloc((size_t)(NBUCK + 1) * 4);
    unsigned int* edges_part  = (unsigned int*)alloc((size_t)E_ * 4);           // 25.6 MB
    float*        dis         = (float*)       alloc((size_t)N_ * 4);           // 0.8 MB
    float*        P           = (float*)       alloc((size_t)N_ * H_ * 4);      // 12.8 MB
    float*        Q           = (float*)       alloc((size_t)N_ * H_ * 4);      // 12.8 MB
    (void)ws_size; (void)in_sizes; (void)n_in; (void)out_size;

    const int gridN = (N_ + 255) / 256;

    k_count  <<<NT, 256, 0, stream>>>(col, cnt_mat);
    k_scan_col<<<NBUCK, 256, 0, stream>>>(cnt_mat, bucketTotal);
    k_scan_top<<<1, 1024, 0, stream>>>(bucketTotal, bucketStart);
    k_addbase<<<(NT * NBUCK + 255) / 256, 256, 0, stream>>>(cnt_mat, bucketStart);
    k_part   <<<NT, 256, 0, stream>>>(row, col, cnt_mat, edges_part);
    k_degB   <<<NBUCK, 256, 0, stream>>>(edges_part, bucketStart, dis);

    k_gemm1s <<<gridN, 256, 0, stream>>>(x, W1, dis, P);
    k_agg<1> <<<NBUCK, 256, 0, stream>>>(P, edges_part, bucketStart, dis, b1, Q);
    k_gemm2s <<<gridN, 256, 0, stream>>>(Q, W2, dis, P);
    k_agg<0> <<<NBUCK, 256, 0, stream>>>(P, edges_part, bucketStart, dis, b2, Q);
    k_pool_fc<<<B_, 64, 0, stream>>>(Q, batch, Wfc, bfc, out);
}

// Round 3
// 1329.411 us; speedup vs baseline: 1.1993x; 1.1993x over previous
//
#include <hip/hip_runtime.h>

#define N_ 200000
#define E_ 6400000
#define F_ 128
#define H_ 16
#define C_ 10
#define B_ 512

#define BSH   8                      // bucket shift: 256 nodes/bucket
#define NBUCK 782                    // ceil(N/256)
#define NT    800                    // partition tiles
#define EPT   8000                   // edges per tile (NT*EPT == E_)
#define NSLICE 4                     // WGs per bucket in aggregation

// ---------- 1. per-tile bucket histogram ----------
__global__ __launch_bounds__(256) void k_count(const int* __restrict__ col, int* __restrict__ cnt_mat) {
    __shared__ int hist[NBUCK];
    int tid = threadIdx.x, tile = blockIdx.x;
    for (int b = tid; b < NBUCK; b += 256) hist[b] = 0;
    __syncthreads();
    const int* c = col + (size_t)tile * EPT;
    for (int i = tid; i < EPT; i += 256) atomicAdd(&hist[c[i] >> BSH], 1);
    __syncthreads();
    for (int b = tid; b < NBUCK; b += 256) cnt_mat[(size_t)tile * NBUCK + b] = hist[b];
}

// ---------- 2. per-bucket column scan (exclusive, in place) + totals ----------
__global__ __launch_bounds__(256) void k_scan_col(int* __restrict__ cnt_mat, int* __restrict__ bucketTotal) {
    __shared__ int s[256];
    int b = blockIdx.x, t = threadIdx.x;
    int v[4];
    int seg = 0;
#pragma unroll
    for (int j = 0; j < 4; ++j) {
        int idx = 4 * t + j;
        v[j] = (idx < NT) ? cnt_mat[(size_t)idx * NBUCK + b] : 0;
        seg += v[j];
    }
    s[t] = seg;
    __syncthreads();
    for (int off = 1; off < 256; off <<= 1) {
        int tmp = (t >= off) ? s[t - off] : 0;
        __syncthreads();
        s[t] += tmp;
        __syncthreads();
    }
    if (t == 255) bucketTotal[b] = s[255];
    int running = s[t] - seg;
#pragma unroll
    for (int j = 0; j < 4; ++j) {
        int idx = 4 * t + j;
        if (idx < NT) {
            int old = v[j];
            cnt_mat[(size_t)idx * NBUCK + b] = running;
            running += old;
        }
    }
}

// ---------- 3. scan bucket totals -> bucketStart[NBUCK+1] ----------
__global__ __launch_bounds__(1024) void k_scan_top(const int* __restrict__ bucketTotal, int* __restrict__ bucketStart) {
    __shared__ int s[1024];
    int t = threadIdx.x;
    int val = (t < NBUCK) ? bucketTotal[t] : 0;
    s[t] = val;
    __syncthreads();
    for (int off = 1; off < 1024; off <<= 1) {
        int tmp = (t >= off) ? s[t - off] : 0;
        __syncthreads();
        s[t] += tmp;
        __syncthreads();
    }
    if (t < NBUCK) bucketStart[t] = s[t] - val;
    if (t == NBUCK - 1) bucketStart[NBUCK] = s[t];   // == E_
}

// ---------- 4. add bucket starts to chunk bases ----------
__global__ __launch_bounds__(256) void k_addbase(int* __restrict__ cnt_mat, const int* __restrict__ bucketStart) {
    int i = blockIdx.x * 256 + threadIdx.x;
    if (i < NT * NBUCK) cnt_mat[i] += bucketStart[i % NBUCK];
}

// ---------- 5. partition edges into buckets (packed: row | c_local<<24) ----------
__global__ __launch_bounds__(256) void k_part(const int* __restrict__ row, const int* __restrict__ col,
                                              const int* __restrict__ cnt_mat, unsigned int* __restrict__ edges_part) {
    __shared__ int cur[NBUCK];
    int tid = threadIdx.x, tile = blockIdx.x;
    for (int b = tid; b < NBUCK; b += 256) cur[b] = cnt_mat[(size_t)tile * NBUCK + b];
    __syncthreads();
    const int* r = row + (size_t)tile * EPT;
    const int* c = col + (size_t)tile * EPT;
    for (int i = tid; i < EPT; i += 256) {
        int cc = c[i];
        int b = cc >> BSH;
        int p = atomicAdd(&cur[b], 1);
        edges_part[p] = (unsigned int)r[i] | ((unsigned int)(cc & 255) << 24);
    }
}

// ---------- 6. per-bucket degree -> dis = rsqrt(1+deg) ----------
__global__ __launch_bounds__(256) void k_degB(const unsigned int* __restrict__ edges_part,
                                              const int* __restrict__ bucketStart, float* __restrict__ dis) {
    __shared__ int cnt[256];
    int b = blockIdx.x, tid = threadIdx.x;
    cnt[tid] = 0;
    __syncthreads();
    int s = bucketStart[b], e = bucketStart[b + 1];
    for (int i = s + tid; i < e; i += 256) atomicAdd(&cnt[edges_part[i] >> 24], 1);
    __syncthreads();
    int n = (b << BSH) + tid;
    if (n < N_) dis[n] = rsqrtf(1.0f + (float)cnt[tid]);
}

// ---------- 7. GEMM1: hws[n][h] = dis[n] * (x[n] @ W1)[h] ----------
__global__ __launch_bounds__(256) void k_gemm1s(const float* __restrict__ x, const float* __restrict__ W1,
                                                const float* __restrict__ dis, float* __restrict__ hws) {
    __shared__ float w[F_ * H_];
    for (int i = threadIdx.x; i < F_ * H_; i += 256) w[i] = W1[i];
    __syncthreads();
    int n = blockIdx.x * 256 + threadIdx.x;
    if (n >= N_) return;
    float acc[H_];
#pragma unroll
    for (int h = 0; h < H_; ++h) acc[h] = 0.f;
    const float4* xr = reinterpret_cast<const float4*>(x + (size_t)n * F_);
#pragma unroll 4
    for (int k4 = 0; k4 < F_ / 4; ++k4) {
        float4 xv = xr[k4];
        int k = k4 * 4;
#pragma unroll
        for (int h = 0; h < H_; ++h) {
            acc[h] += xv.x * w[(k + 0) * H_ + h] + xv.y * w[(k + 1) * H_ + h]
                    + xv.z * w[(k + 2) * H_ + h] + xv.w * w[(k + 3) * H_ + h];
        }
    }
    float dn = dis[n];
    float* o = hws + (size_t)n * H_;
#pragma unroll
    for (int h = 0; h < H_; h += 4)
        *(float4*)(o + h) = make_float4(acc[h] * dn, acc[h + 1] * dn, acc[h + 2] * dn, acc[h + 3] * dn);
}

// ---------- GEMM2: hws[n][h] = dis[n] * (hin[n] @ W2)[h] ----------
__global__ __launch_bounds__(256) void k_gemm2s(const float* __restrict__ hin, const float* __restrict__ W2,
                                                const float* __restrict__ dis, float* __restrict__ hws) {
    __shared__ float w[H_ * H_];
    if (threadIdx.x < H_ * H_) w[threadIdx.x] = W2[threadIdx.x];
    __syncthreads();
    int n = blockIdx.x * 256 + threadIdx.x;
    if (n >= N_) return;
    float hv[H_];
    const float4* hr = reinterpret_cast<const float4*>(hin + (size_t)n * H_);
#pragma unroll
    for (int q = 0; q < 4; ++q) {
        float4 v = hr[q];
        hv[q * 4 + 0] = v.x; hv[q * 4 + 1] = v.y; hv[q * 4 + 2] = v.z; hv[q * 4 + 3] = v.w;
    }
    float acc[H_];
#pragma unroll
    for (int h = 0; h < H_; ++h) acc[h] = 0.f;
#pragma unroll
    for (int k = 0; k < H_; ++k)
#pragma unroll
        for (int h = 0; h < H_; ++h) acc[h] += hv[k] * w[k * H_ + h];
    float dn = dis[n];
    float* o = hws + (size_t)n * H_;
#pragma unroll
    for (int h = 0; h < H_; h += 4)
        *(float4*)(o + h) = make_float4(acc[h] * dn, acc[h + 1] * dn, acc[h + 2] * dn, acc[h + 3] * dn);
}

// ---------- init: Q[n][h] = dis[n]*hws[n][h] + bias[h]  (self-loop + bias) ----------
__global__ __launch_bounds__(256) void k_init(const float* __restrict__ hws, const float* __restrict__ dis,
                                              const float* __restrict__ bias, float* __restrict__ Q) {
    int t = blockIdx.x * 256 + threadIdx.x;
    if (t >= N_ * H_) return;
    int n = t >> 4, h = t & 15;
    Q[t] = dis[n] * hws[t] + bias[h];
}

// ---------- aggregation: slice of one bucket, LDS accumulate, atomic combine ----------
// adds dis[n] * sum_{edges in slice -> n} hws[r][h] into Q[n][h]
__global__ __launch_bounds__(256) void k_aggS(const float* __restrict__ hws, const unsigned int* __restrict__ edges_part,
                                              const int* __restrict__ bucketStart, const float* __restrict__ dis,
                                              float* __restrict__ Q) {
    __shared__ float acc[256 * 17];              // pad stride 17 -> spread banks
    int b = blockIdx.x >> 2, slice = blockIdx.x & (NSLICE - 1);
    int tid = threadIdx.x;
    for (int i = tid; i < 256 * 17; i += 256) acc[i] = 0.f;
    __syncthreads();
    int s = bucketStart[b], e = bucketStart[b + 1];
    int len = e - s;
    int ss = s + ((len * slice) >> 2);
    int ee = s + ((len * (slice + 1)) >> 2);
    int g = tid >> 4, h = tid & 15;
#pragma unroll 2
    for (int p = ss + g; p < ee; p += 16) {
        unsigned int pk = edges_part[p];
        int r = pk & 0x00FFFFFFu;
        int cl = pk >> 24;
        atomicAdd(&acc[cl * 17 + h], hws[r * 16 + h]);
    }
    __syncthreads();
    int base = (b << BSH) * H_;
    for (int i = tid; i < 256 * H_; i += 256) {
        int cl = i >> 4, hh = i & 15;
        int n = (b << BSH) + cl;
        float v = acc[cl * 17 + hh];
        if (n < N_ && v != 0.f) atomicAdd(&Q[base + i], dis[n] * v);
    }
}

// ---------- relu in place ----------
__global__ __launch_bounds__(256) void k_relu(float* __restrict__ Q) {
    int t = blockIdx.x * 256 + threadIdx.x;
    if (t < N_ * H_) Q[t] = fmaxf(Q[t], 0.f);
}

// ---------- pool + fc (256 threads/graph) ----------
__global__ __launch_bounds__(256) void k_pool_fc(const float* __restrict__ h2, const int* __restrict__ batch,
                                                 const float* __restrict__ Wfc, const float* __restrict__ bfc,
                                                 float* __restrict__ out) {
    int b = blockIdx.x;
    int lo = 0, hi = N_;
    while (lo < hi) { int m = (lo + hi) >> 1; if (batch[m] < b) lo = m + 1; else hi = m; }
    int start = lo;
    lo = start; hi = N_;
    while (lo < hi) { int m = (lo + hi) >> 1; if (batch[m] < b + 1) lo = m + 1; else hi = m; }
    int end = lo;

    int t = threadIdx.x;
    int h = t & 15, q = t >> 4;                 // 16 node-lanes x 16 h
    float acc = 0.f;
    for (int n = start + q; n < end; n += 16) acc += h2[n * H_ + h];
    acc += __shfl_xor(acc, 16);
    acc += __shfl_xor(acc, 32);                 // wave-local sum over its 4 q's

    __shared__ float part[4][H_];
    __shared__ float pooled[H_];
    if ((t & 63) < 16) part[t >> 6][h] = acc;
    __syncthreads();
    if (t < H_) {
        float s2 = part[0][t] + part[1][t] + part[2][t] + part[3][t];
        pooled[t] = s2 / fmaxf((float)(end - start), 1.0f);
    }
    __syncthreads();
    if (t < C_) {
        float o = bfc[t];
#pragma unroll
        for (int hh = 0; hh < H_; ++hh) o += pooled[hh] * Wfc[hh * C_ + t];
        out[b * C_ + t] = o;
    }
}

extern "C" void kernel_launch(void* const* d_in, const int* in_sizes, int n_in,
                              void* d_out, int out_size, void* d_ws, size_t ws_size,
                              hipStream_t stream) {
    const float* x    = (const float*)d_in[0];
    const int*   ei   = (const int*)d_in[1];
    const int*   batch= (const int*)d_in[2];
    const float* W1   = (const float*)d_in[3];
    const float* b1   = (const float*)d_in[4];
    const float* W2   = (const float*)d_in[5];
    const float* b2   = (const float*)d_in[6];
    const float* Wfc  = (const float*)d_in[7];
    const float* bfc  = (const float*)d_in[8];
    float* out = (float*)d_out;

    const int* row = ei;
    const int* col = ei + E_;

    size_t off = 0;
    auto alloc = [&](size_t bytes) -> void* {
        void* p = (char*)d_ws + off;
        off += (bytes + 255) & ~(size_t)255;
        return p;
    };
    int*          cnt_mat     = (int*)         alloc((size_t)NT * NBUCK * 4);   // 2.5 MB
    int*          bucketTotal = (int*)         alloc((size_t)NBUCK * 4);
    int*          bucketStart = (int*)         alloc((size_t)(NBUCK + 1) * 4);
    unsigned int* edges_part  = (unsigned int*)alloc((size_t)E_ * 4);           // 25.6 MB
    float*        dis         = (float*)       alloc((size_t)N_ * 4);           // 0.8 MB
    float*        P           = (float*)       alloc((size_t)N_ * H_ * 4);      // 12.8 MB
    float*        Q           = (float*)       alloc((size_t)N_ * H_ * 4);      // 12.8 MB
    (void)ws_size; (void)in_sizes; (void)n_in; (void)out_size;

    const int gridN  = (N_ + 255) / 256;
    const int gridNH = (N_ * H_ + 255) / 256;

    k_count   <<<NT, 256, 0, stream>>>(col, cnt_mat);
    k_scan_col<<<NBUCK, 256, 0, stream>>>(cnt_mat, bucketTotal);
    k_scan_top<<<1, 1024, 0, stream>>>(bucketTotal, bucketStart);
    k_addbase <<<(NT * NBUCK + 255) / 256, 256, 0, stream>>>(cnt_mat, bucketStart);
    k_part    <<<NT, 256, 0, stream>>>(row, col, cnt_mat, edges_part);
    k_degB    <<<NBUCK, 256, 0, stream>>>(edges_part, bucketStart, dis);

    // conv1
    k_gemm1s<<<gridN, 256, 0, stream>>>(x, W1, dis, P);
    k_init  <<<gridNH, 256, 0, stream>>>(P, dis, b1, Q);
    k_aggS  <<<NBUCK * NSLICE, 256, 0, stream>>>(P, edges_part, bucketStart, dis, Q);
    k_relu  <<<gridNH, 256, 0, stream>>>(Q);
    // conv2
    k_gemm2s<<<gridN, 256, 0, stream>>>(Q, W2, dis, P);
    k_init  <<<gridNH, 256, 0, stream>>>(P, dis, b2, Q);
    k_aggS  <<<NBUCK * NSLICE, 256, 0, stream>>>(P, edges_part, bucketStart, dis, Q);

    k_pool_fc<<<B_, 256, 0, stream>>>(Q, batch, Wfc, bfc, out);
}

// Round 4
// 1312.623 us; speedup vs baseline: 1.2146x; 1.0128x over previous
//
#include <hip/hip_runtime.h>

#define N_ 200000
#define E_ 6400000
#define F_ 128
#define H_ 16
#define C_ 10
#define B_ 512

#define BSH   8                      // bucket shift: 256 nodes/bucket
#define NBUCK 782                    // ceil(N/256)
#define NT    800                    // partition tiles
#define EPT   8000                   // edges per tile (NT*EPT == E_)
#define NSLICE 4                     // WGs per bucket in aggregation
#define ECHUNK 2048                  // staged edges per chunk

// ---------- 1. per-tile bucket histogram ----------
__global__ __launch_bounds__(256) void k_count(const int* __restrict__ col, int* __restrict__ cnt_mat) {
    __shared__ int hist[NBUCK];
    int tid = threadIdx.x, tile = blockIdx.x;
    for (int b = tid; b < NBUCK; b += 256) hist[b] = 0;
    __syncthreads();
    const int* c = col + (size_t)tile * EPT;
    for (int i = tid; i < EPT; i += 256) atomicAdd(&hist[c[i] >> BSH], 1);
    __syncthreads();
    for (int b = tid; b < NBUCK; b += 256) cnt_mat[(size_t)tile * NBUCK + b] = hist[b];
}

// ---------- 2. per-bucket column scan (exclusive, in place) + totals ----------
__global__ __launch_bounds__(256) void k_scan_col(int* __restrict__ cnt_mat, int* __restrict__ bucketTotal) {
    __shared__ int s[256];
    int b = blockIdx.x, t = threadIdx.x;
    int v[4];
    int seg = 0;
#pragma unroll
    for (int j = 0; j < 4; ++j) {
        int idx = 4 * t + j;
        v[j] = (idx < NT) ? cnt_mat[(size_t)idx * NBUCK + b] : 0;
        seg += v[j];
    }
    s[t] = seg;
    __syncthreads();
    for (int off = 1; off < 256; off <<= 1) {
        int tmp = (t >= off) ? s[t - off] : 0;
        __syncthreads();
        s[t] += tmp;
        __syncthreads();
    }
    if (t == 255) bucketTotal[b] = s[255];
    int running = s[t] - seg;
#pragma unroll
    for (int j = 0; j < 4; ++j) {
        int idx = 4 * t + j;
        if (idx < NT) {
            int old = v[j];
            cnt_mat[(size_t)idx * NBUCK + b] = running;
            running += old;
        }
    }
}

// ---------- 3. scan bucket totals -> bucketStart[NBUCK+1] ----------
__global__ __launch_bounds__(1024) void k_scan_top(const int* __restrict__ bucketTotal, int* __restrict__ bucketStart) {
    __shared__ int s[1024];
    int t = threadIdx.x;
    int val = (t < NBUCK) ? bucketTotal[t] : 0;
    s[t] = val;
    __syncthreads();
    for (int off = 1; off < 1024; off <<= 1) {
        int tmp = (t >= off) ? s[t - off] : 0;
        __syncthreads();
        s[t] += tmp;
        __syncthreads();
    }
    if (t < NBUCK) bucketStart[t] = s[t] - val;
    if (t == NBUCK - 1) bucketStart[NBUCK] = s[t];   // == E_
}

// ---------- 4. add bucket starts to chunk bases ----------
__global__ __launch_bounds__(256) void k_addbase(int* __restrict__ cnt_mat, const int* __restrict__ bucketStart) {
    int i = blockIdx.x * 256 + threadIdx.x;
    if (i < NT * NBUCK) cnt_mat[i] += bucketStart[i % NBUCK];
}

// ---------- 5. partition edges into buckets (packed: row | c_local<<24) ----------
__global__ __launch_bounds__(256) void k_part(const int* __restrict__ row, const int* __restrict__ col,
                                              const int* __restrict__ cnt_mat, unsigned int* __restrict__ edges_part) {
    __shared__ int cur[NBUCK];
    int tid = threadIdx.x, tile = blockIdx.x;
    for (int b = tid; b < NBUCK; b += 256) cur[b] = cnt_mat[(size_t)tile * NBUCK + b];
    __syncthreads();
    const int* r = row + (size_t)tile * EPT;
    const int* c = col + (size_t)tile * EPT;
    for (int i = tid; i < EPT; i += 256) {
        int cc = c[i];
        int b = cc >> BSH;
        int p = atomicAdd(&cur[b], 1);
        edges_part[p] = (unsigned int)r[i] | ((unsigned int)(cc & 255) << 24);
    }
}

// ---------- 6. per-bucket degree -> dis = rsqrt(1+deg) ----------
__global__ __launch_bounds__(256) void k_degB(const unsigned int* __restrict__ edges_part,
                                              const int* __restrict__ bucketStart, float* __restrict__ dis) {
    __shared__ int cnt[256];
    int b = blockIdx.x, tid = threadIdx.x;
    cnt[tid] = 0;
    __syncthreads();
    int s = bucketStart[b], e = bucketStart[b + 1];
    for (int i = s + tid; i < e; i += 256) atomicAdd(&cnt[edges_part[i] >> 24], 1);
    __syncthreads();
    int n = (b << BSH) + tid;
    if (n < N_) dis[n] = rsqrtf(1.0f + (float)cnt[tid]);
}

// ---------- 7. GEMM1: P = dis*(x@W1), Qinit = dis*P + b1 ----------
__global__ __launch_bounds__(256) void k_gemm1s(const float* __restrict__ x, const float* __restrict__ W1,
                                                const float* __restrict__ dis, const float* __restrict__ bias,
                                                float* __restrict__ P, float* __restrict__ Qinit) {
    __shared__ float w[F_ * H_];
    __shared__ float bsh[H_];
    for (int i = threadIdx.x; i < F_ * H_; i += 256) w[i] = W1[i];
    if (threadIdx.x < H_) bsh[threadIdx.x] = bias[threadIdx.x];
    __syncthreads();
    int n = blockIdx.x * 256 + threadIdx.x;
    if (n >= N_) return;
    float acc[H_];
#pragma unroll
    for (int h = 0; h < H_; ++h) acc[h] = 0.f;
    const float4* xr = reinterpret_cast<const float4*>(x + (size_t)n * F_);
#pragma unroll 4
    for (int k4 = 0; k4 < F_ / 4; ++k4) {
        float4 xv = xr[k4];
        int k = k4 * 4;
#pragma unroll
        for (int h = 0; h < H_; ++h) {
            acc[h] += xv.x * w[(k + 0) * H_ + h] + xv.y * w[(k + 1) * H_ + h]
                    + xv.z * w[(k + 2) * H_ + h] + xv.w * w[(k + 3) * H_ + h];
        }
    }
    float dn = dis[n];
    float* o = P + (size_t)n * H_;
    float* q = Qinit + (size_t)n * H_;
#pragma unroll
    for (int h = 0; h < H_; h += 4) {
        float p0 = acc[h] * dn, p1 = acc[h + 1] * dn, p2 = acc[h + 2] * dn, p3 = acc[h + 3] * dn;
        *(float4*)(o + h) = make_float4(p0, p1, p2, p3);
        *(float4*)(q + h) = make_float4(p0 * dn + bsh[h], p1 * dn + bsh[h + 1],
                                        p2 * dn + bsh[h + 2], p3 * dn + bsh[h + 3]);
    }
}

// ---------- GEMM2 (relu on input): P = dis*(relu(hin)@W2), Qinit = dis*P + b2 ----------
__global__ __launch_bounds__(256) void k_gemm2s(const float* __restrict__ hin, const float* __restrict__ W2,
                                                const float* __restrict__ dis, const float* __restrict__ bias,
                                                float* __restrict__ P, float* __restrict__ Qinit) {
    __shared__ float w[H_ * H_];
    __shared__ float bsh[H_];
    if (threadIdx.x < H_ * H_) w[threadIdx.x] = W2[threadIdx.x];
    if (threadIdx.x < H_) bsh[threadIdx.x] = bias[threadIdx.x];
    __syncthreads();
    int n = blockIdx.x * 256 + threadIdx.x;
    if (n >= N_) return;
    float hv[H_];
    const float4* hr = reinterpret_cast<const float4*>(hin + (size_t)n * H_);
#pragma unroll
    for (int q = 0; q < 4; ++q) {
        float4 v = hr[q];
        hv[q * 4 + 0] = fmaxf(v.x, 0.f); hv[q * 4 + 1] = fmaxf(v.y, 0.f);
        hv[q * 4 + 2] = fmaxf(v.z, 0.f); hv[q * 4 + 3] = fmaxf(v.w, 0.f);
    }
    float acc[H_];
#pragma unroll
    for (int h = 0; h < H_; ++h) acc[h] = 0.f;
#pragma unroll
    for (int k = 0; k < H_; ++k)
#pragma unroll
        for (int h = 0; h < H_; ++h) acc[h] += hv[k] * w[k * H_ + h];
    float dn = dis[n];
    float* o = P + (size_t)n * H_;
    float* q = Qinit + (size_t)n * H_;
#pragma unroll
    for (int h = 0; h < H_; h += 4) {
        float p0 = acc[h] * dn, p1 = acc[h + 1] * dn, p2 = acc[h + 2] * dn, p3 = acc[h + 3] * dn;
        *(float4*)(o + h) = make_float4(p0, p1, p2, p3);
        *(float4*)(q + h) = make_float4(p0 * dn + bsh[h], p1 * dn + bsh[h + 1],
                                        p2 * dn + bsh[h + 2], p3 * dn + bsh[h + 3]);
    }
}

// ---------- aggregation: stage edges in LDS, 8-wide batched gathers ----------
// adds dis[n] * sum_{edges in slice -> n} hws[r][h] into Q[n][h]
__global__ __launch_bounds__(256) void k_aggS(const float* __restrict__ hws, const unsigned int* __restrict__ edges_part,
                                              const int* __restrict__ bucketStart, const float* __restrict__ dis,
                                              float* __restrict__ Q) {
    __shared__ float acc[256 * 17];              // 17 KB, pad stride 17
    __shared__ unsigned int est[ECHUNK];         // 8 KB
    int b = blockIdx.x >> 2, slice = blockIdx.x & (NSLICE - 1);
    int tid = threadIdx.x;
    for (int i = tid; i < 256 * 17; i += 256) acc[i] = 0.f;
    int s = bucketStart[b], e = bucketStart[b + 1];
    int len = e - s;
    int ss = s + ((len * slice) >> 2);
    int ee = s + ((len * (slice + 1)) >> 2);
    int g = tid >> 4, h = tid & 15;

    for (int chunk = ss; chunk < ee; chunk += ECHUNK) {
        int mc = min(ECHUNK, ee - chunk);
        __syncthreads();                          // acc/est ready for reuse
        for (int i = tid; i < mc; i += 256) est[i] = edges_part[chunk + i];
        __syncthreads();

        int i = g;
        for (; i + 113 <= mc; i += 128) {         // 8 edges per group per stage
            unsigned int pk0 = est[i      ], pk1 = est[i +  16], pk2 = est[i +  32], pk3 = est[i +  48];
            unsigned int pk4 = est[i +  64], pk5 = est[i +  80], pk6 = est[i +  96], pk7 = est[i + 112];
            float v0 = hws[(pk0 & 0xFFFFFFu) * 16 + h];
            float v1 = hws[(pk1 & 0xFFFFFFu) * 16 + h];
            float v2 = hws[(pk2 & 0xFFFFFFu) * 16 + h];
            float v3 = hws[(pk3 & 0xFFFFFFu) * 16 + h];
            float v4 = hws[(pk4 & 0xFFFFFFu) * 16 + h];
            float v5 = hws[(pk5 & 0xFFFFFFu) * 16 + h];
            float v6 = hws[(pk6 & 0xFFFFFFu) * 16 + h];
            float v7 = hws[(pk7 & 0xFFFFFFu) * 16 + h];
            atomicAdd(&acc[(pk0 >> 24) * 17 + h], v0);
            atomicAdd(&acc[(pk1 >> 24) * 17 + h], v1);
            atomicAdd(&acc[(pk2 >> 24) * 17 + h], v2);
            atomicAdd(&acc[(pk3 >> 24) * 17 + h], v3);
            atomicAdd(&acc[(pk4 >> 24) * 17 + h], v4);
            atomicAdd(&acc[(pk5 >> 24) * 17 + h], v5);
            atomicAdd(&acc[(pk6 >> 24) * 17 + h], v6);
            atomicAdd(&acc[(pk7 >> 24) * 17 + h], v7);
        }
        for (; i < mc; i += 16) {
            unsigned int pk = est[i];
            atomicAdd(&acc[(pk >> 24) * 17 + h], hws[(pk & 0xFFFFFFu) * 16 + h]);
        }
    }
    __syncthreads();
    int base = (b << BSH) * H_;
    for (int i = tid; i < 256 * H_; i += 256) {
        int cl = i >> 4;
        int n = (b << BSH) + cl;
        float v = acc[cl * 17 + (i & 15)];
        if (n < N_ && v != 0.f) atomicAdd(&Q[base + i], dis[n] * v);
    }
}

// ---------- pool + fc (256 threads/graph) ----------
__global__ __launch_bounds__(256) void k_pool_fc(const float* __restrict__ h2, const int* __restrict__ batch,
                                                 const float* __restrict__ Wfc, const float* __restrict__ bfc,
                                                 float* __restrict__ out) {
    int b = blockIdx.x;
    int lo = 0, hi = N_;
    while (lo < hi) { int m = (lo + hi) >> 1; if (batch[m] < b) lo = m + 1; else hi = m; }
    int start = lo;
    lo = start; hi = N_;
    while (lo < hi) { int m = (lo + hi) >> 1; if (batch[m] < b + 1) lo = m + 1; else hi = m; }
    int end = lo;

    int t = threadIdx.x;
    int h = t & 15, q = t >> 4;
    float acc = 0.f;
    for (int n = start + q; n < end; n += 16) acc += h2[n * H_ + h];
    acc += __shfl_xor(acc, 16);
    acc += __shfl_xor(acc, 32);

    __shared__ float part[4][H_];
    __shared__ float pooled[H_];
    if ((t & 63) < 16) part[t >> 6][h] = acc;
    __syncthreads();
    if (t < H_) {
        float s2 = part[0][t] + part[1][t] + part[2][t] + part[3][t];
        pooled[t] = s2 / fmaxf((float)(end - start), 1.0f);
    }
    __syncthreads();
    if (t < C_) {
        float o = bfc[t];
#pragma unroll
        for (int hh = 0; hh < H_; ++hh) o += pooled[hh] * Wfc[hh * C_ + t];
        out[b * C_ + t] = o;
    }
}

extern "C" void kernel_launch(void* const* d_in, const int* in_sizes, int n_in,
                              void* d_out, int out_size, void* d_ws, size_t ws_size,
                              hipStream_t stream) {
    const float* x    = (const float*)d_in[0];
    const int*   ei   = (const int*)d_in[1];
    const int*   batch= (const int*)d_in[2];
    const float* W1   = (const float*)d_in[3];
    const float* b1   = (const float*)d_in[4];
    const float* W2   = (const float*)d_in[5];
    const float* b2   = (const float*)d_in[6];
    const float* Wfc  = (const float*)d_in[7];
    const float* bfc  = (const float*)d_in[8];
    float* out = (float*)d_out;

    const int* row = ei;
    const int* col = ei + E_;

    size_t off = 0;
    auto alloc = [&](size_t bytes) -> void* {
        void* p = (char*)d_ws + off;
        off += (bytes + 255) & ~(size_t)255;
        return p;
    };
    int*          cnt_mat     = (int*)         alloc((size_t)NT * NBUCK * 4);   // 2.5 MB
    int*          bucketTotal = (int*)         alloc((size_t)NBUCK * 4);
    int*          bucketStart = (int*)         alloc((size_t)(NBUCK + 1) * 4);
    unsigned int* edges_part  = (unsigned int*)alloc((size_t)E_ * 4);           // 25.6 MB
    float*        dis         = (float*)       alloc((size_t)N_ * 4);           // 0.8 MB
    float*        P           = (float*)       alloc((size_t)N_ * H_ * 4);      // 12.8 MB
    float*        Q           = (float*)       alloc((size_t)N_ * H_ * 4);      // 12.8 MB
    (void)ws_size; (void)in_sizes; (void)n_in; (void)out_size;

    const int gridN = (N_ + 255) / 256;

    k_count   <<<NT, 256, 0, stream>>>(col, cnt_mat);
    k_scan_col<<<NBUCK, 256, 0, stream>>>(cnt_mat, bucketTotal);
    k_scan_top<<<1, 1024, 0, stream>>>(bucketTotal, bucketStart);
    k_addbase <<<(NT * NBUCK + 255) / 256, 256, 0, stream>>>(cnt_mat, bucketStart);
    k_part    <<<NT, 256, 0, stream>>>(row, col, cnt_mat, edges_part);
    k_degB    <<<NBUCK, 256, 0, stream>>>(edges_part, bucketStart, dis);

    // conv1: P = dis*(x@W1), Q = dis*P + b1, then scatter-add edges
    k_gemm1s<<<gridN, 256, 0, stream>>>(x, W1, dis, b1, P, Q);
    k_aggS  <<<NBUCK * NSLICE, 256, 0, stream>>>(P, edges_part, bucketStart, dis, Q);
    // conv2: relu fused into input load
    k_gemm2s<<<gridN, 256, 0, stream>>>(Q, W2, dis, b2, P, Q);   // NOTE: reads Q fully before overwriting same n? NO — see below
    k_aggS  <<<NBUCK * NSLICE, 256, 0, stream>>>(P, edges_part, bucketStart, dis, Q);

    k_pool_fc<<<B_, 256, 0, stream>>>(Q, batch, Wfc, bfc, out);
}

// Round 5
// 582.032 us; speedup vs baseline: 2.7392x; 2.2552x over previous
//
#include <hip/hip_runtime.h>

#define N_ 200000
#define E_ 6400000
#define F_ 128
#define H_ 16
#define C_ 10
#define B_ 512

#define BSH   8                      // dst bucket = dst>>8  (256 nodes)
#define NBUCK 782                    // ceil(N/256)
#define CHSH  15                     // src chunk = src>>15 (32768 rows = 2MB of P)
#define NCH   7                      // ceil(200000/32768)
#define NKEY  (NCH * NBUCK)          // 5474
#define NT    250                    // partition tiles
#define EPT   25600                  // edges per tile (NT*EPT == E_)
#define N1    (N_ + 1)
#define NPB   12500                  // agg blocks per pass = N_*H_/256
#define STAGE 4096                   // part2 LDS staging cap

// ---------- 1. per-tile key histogram (key = chunk*NBUCK + bucket) ----------
__global__ __launch_bounds__(256) void k_count(const int* __restrict__ row, const int* __restrict__ col,
                                               int* __restrict__ cnt_mat) {
    __shared__ int hist[NKEY];
    int tid = threadIdx.x, tile = blockIdx.x;
    for (int i = tid; i < NKEY; i += 256) hist[i] = 0;
    __syncthreads();
    const int* r = row + (size_t)tile * EPT;
    const int* c = col + (size_t)tile * EPT;
    for (int i = tid; i < EPT; i += 256) {
        int key = (r[i] >> CHSH) * NBUCK + (c[i] >> BSH);
        atomicAdd(&hist[key], 1);
    }
    __syncthreads();
    for (int i = tid; i < NKEY; i += 256) cnt_mat[(size_t)i * NT + tile] = hist[i];   // key-major
}

// ---------- 2. per-key scan over tiles (exclusive, in place) + totals ----------
__global__ __launch_bounds__(256) void k_scan_col(int* __restrict__ cnt_mat, int* __restrict__ keyTotal) {
    __shared__ int s[256];
    int k = blockIdx.x, t = threadIdx.x;
    int v = (t < NT) ? cnt_mat[(size_t)k * NT + t] : 0;
    s[t] = v;
    __syncthreads();
    for (int off = 1; off < 256; off <<= 1) {
        int tmp = (t >= off) ? s[t - off] : 0;
        __syncthreads();
        s[t] += tmp;
        __syncthreads();
    }
    if (t == 255) keyTotal[k] = s[255];
    if (t < NT) cnt_mat[(size_t)k * NT + t] = s[t] - v;
}

// ---------- 3. scan key totals -> keyStart[NKEY+1] ----------
__global__ __launch_bounds__(1024) void k_scan_top(const int* __restrict__ keyTotal, int* __restrict__ keyStart) {
    __shared__ int s[1024];
    __shared__ int base;
    int t = threadIdx.x;
    if (t == 0) base = 0;
    __syncthreads();
    for (int tile = 0; tile < (NKEY + 1023) / 1024; ++tile) {
        int idx = tile * 1024 + t;
        int v = (idx < NKEY) ? keyTotal[idx] : 0;
        s[t] = v;
        __syncthreads();
        for (int off = 1; off < 1024; off <<= 1) {
            int tmp = (t >= off) ? s[t - off] : 0;
            __syncthreads();
            s[t] += tmp;
            __syncthreads();
        }
        if (idx < NKEY) keyStart[idx] = base + s[t] - v;
        __syncthreads();
        if (t == 0) base += s[1023];
        __syncthreads();
    }
    if (t == 0) keyStart[NKEY] = base;   // == E_
}

// ---------- 4. partition edges by key (packed: src | c_local<<24) ----------
__global__ __launch_bounds__(256) void k_part(const int* __restrict__ row, const int* __restrict__ col,
                                              const int* __restrict__ cnt_mat, const int* __restrict__ keyStart,
                                              unsigned int* __restrict__ edges_part) {
    __shared__ int cur[NKEY];
    int tid = threadIdx.x, tile = blockIdx.x;
    for (int i = tid; i < NKEY; i += 256) cur[i] = cnt_mat[(size_t)i * NT + tile] + keyStart[i];
    __syncthreads();
    const int* r = row + (size_t)tile * EPT;
    const int* c = col + (size_t)tile * EPT;
    for (int i = tid; i < EPT; i += 256) {
        int src = r[i], dst = c[i];
        int key = (src >> CHSH) * NBUCK + (dst >> BSH);
        int p = atomicAdd(&cur[key], 1);
        edges_part[p] = (unsigned int)src | ((unsigned int)(dst & 255) << 24);
    }
}

// ---------- 5. in-partition counting sort by dst local; write NCO; strip to plain src ----------
__global__ __launch_bounds__(256) void k_part2(unsigned int* __restrict__ edges_part, const int* __restrict__ keyStart,
                                               int* __restrict__ NCO, unsigned int* __restrict__ spill) {
    __shared__ unsigned int stg[STAGE];   // 16 KB
    __shared__ int cnt[256];
    __shared__ int scn[256];
    __shared__ int cur[256];
    int k = blockIdx.x, tid = threadIdx.x;
    int s = keyStart[k], e = keyStart[k + 1], len = e - s;
    int bucket = k % NBUCK, chunk = k / NBUCK;
    cnt[tid] = 0;
    __syncthreads();
    bool small = (len <= STAGE);
    if (small) {
        for (int i = tid; i < len; i += 256) stg[i] = edges_part[s + i];
        __syncthreads();
        for (int i = tid; i < len; i += 256) atomicAdd(&cnt[stg[i] >> 24], 1);
    } else {   // never expected with this input; correct fallback via spill (P/Q region, unused yet)
        for (int i = tid; i < len; i += 256) {
            unsigned int w = edges_part[s + i];
            spill[s + i] = w;
            atomicAdd(&cnt[w >> 24], 1);
        }
    }
    __syncthreads();
    int v = cnt[tid];
    scn[tid] = v;
    __syncthreads();
    for (int off = 1; off < 256; off <<= 1) {
        int tmp = (tid >= off) ? scn[tid - off] : 0;
        __syncthreads();
        scn[tid] += tmp;
        __syncthreads();
    }
    int excl = scn[tid] - v;
    cur[tid] = excl;
    int n = (bucket << BSH) + tid;
    if (n < N_) NCO[(size_t)chunk * N1 + n] = s + excl;
    __syncthreads();
    if (small) {
        for (int i = tid; i < len; i += 256) {
            unsigned int w = stg[i];
            int pos = atomicAdd(&cur[w >> 24], 1);
            edges_part[s + pos] = w & 0xFFFFFFu;
        }
    } else {
        for (int i = tid; i < len; i += 256) {
            unsigned int w = spill[s + i];
            int pos = atomicAdd(&cur[w >> 24], 1);
            edges_part[s + pos] = w & 0xFFFFFFu;
        }
    }
}

// ---------- 6. NCO sentinels ----------
__global__ void k_sent(const int* __restrict__ keyStart, int* __restrict__ NCO) {
    int t = threadIdx.x;
    if (t < NCH) NCO[(size_t)t * N1 + N_] = keyStart[(t + 1) * NBUCK];
}

// ---------- 7. dis from NCO degree sums ----------
__global__ __launch_bounds__(256) void k_disNCO(const int* __restrict__ NCO, float* __restrict__ dis) {
    int n = blockIdx.x * 256 + threadIdx.x;
    if (n >= N_) return;
    int deg = 0;
#pragma unroll
    for (int c = 0; c < NCH; ++c) deg += NCO[(size_t)c * N1 + n + 1] - NCO[(size_t)c * N1 + n];
    dis[n] = rsqrtf(1.0f + (float)deg);
}

// ---------- 8. GEMM1: P = dis*(x@W1), Qinit = dis*P + b1 ----------
__global__ __launch_bounds__(256) void k_gemm1s(const float* __restrict__ x, const float* __restrict__ W1,
                                                const float* __restrict__ dis, const float* __restrict__ bias,
                                                float* __restrict__ P, float* __restrict__ Qinit) {
    __shared__ float w[F_ * H_];
    __shared__ float bsh[H_];
    for (int i = threadIdx.x; i < F_ * H_; i += 256) w[i] = W1[i];
    if (threadIdx.x < H_) bsh[threadIdx.x] = bias[threadIdx.x];
    __syncthreads();
    int n = blockIdx.x * 256 + threadIdx.x;
    if (n >= N_) return;
    float acc[H_];
#pragma unroll
    for (int h = 0; h < H_; ++h) acc[h] = 0.f;
    const float4* xr = reinterpret_cast<const float4*>(x + (size_t)n * F_);
#pragma unroll 4
    for (int k4 = 0; k4 < F_ / 4; ++k4) {
        float4 xv = xr[k4];
        int k = k4 * 4;
#pragma unroll
        for (int h = 0; h < H_; ++h) {
            acc[h] += xv.x * w[(k + 0) * H_ + h] + xv.y * w[(k + 1) * H_ + h]
                    + xv.z * w[(k + 2) * H_ + h] + xv.w * w[(k + 3) * H_ + h];
        }
    }
    float dn = dis[n];
    float* o = P + (size_t)n * H_;
    float* q = Qinit + (size_t)n * H_;
#pragma unroll
    for (int h = 0; h < H_; h += 4) {
        float p0 = acc[h] * dn, p1 = acc[h + 1] * dn, p2 = acc[h + 2] * dn, p3 = acc[h + 3] * dn;
        *(float4*)(o + h) = make_float4(p0, p1, p2, p3);
        *(float4*)(q + h) = make_float4(p0 * dn + bsh[h], p1 * dn + bsh[h + 1],
                                        p2 * dn + bsh[h + 2], p3 * dn + bsh[h + 3]);
    }
}

// ---------- 10. GEMM2 (relu fused on input): P = dis*(relu(hin)@W2), Qinit = dis*P + b2 ----------
__global__ __launch_bounds__(256) void k_gemm2s(const float* __restrict__ hin, const float* __restrict__ W2,
                                                const float* __restrict__ dis, const float* __restrict__ bias,
                                                float* __restrict__ P, float* __restrict__ Qinit) {
    __shared__ float w[H_ * H_];
    __shared__ float bsh[H_];
    if (threadIdx.x < H_ * H_) w[threadIdx.x] = W2[threadIdx.x];
    if (threadIdx.x < H_) bsh[threadIdx.x] = bias[threadIdx.x];
    __syncthreads();
    int n = blockIdx.x * 256 + threadIdx.x;
    if (n >= N_) return;
    float hv[H_];
    const float4* hr = reinterpret_cast<const float4*>(hin + (size_t)n * H_);
#pragma unroll
    for (int q = 0; q < 4; ++q) {
        float4 v = hr[q];
        hv[q * 4 + 0] = fmaxf(v.x, 0.f); hv[q * 4 + 1] = fmaxf(v.y, 0.f);
        hv[q * 4 + 2] = fmaxf(v.z, 0.f); hv[q * 4 + 3] = fmaxf(v.w, 0.f);
    }
    float acc[H_];
#pragma unroll
    for (int h = 0; h < H_; ++h) acc[h] = 0.f;
#pragma unroll
    for (int k = 0; k < H_; ++k)
#pragma unroll
        for (int h = 0; h < H_; ++h) acc[h] += hv[k] * w[k * H_ + h];
    float dn = dis[n];
    float* o = P + (size_t)n * H_;
    float* q = Qinit + (size_t)n * H_;
#pragma unroll
    for (int h = 0; h < H_; h += 4) {
        float p0 = acc[h] * dn, p1 = acc[h + 1] * dn, p2 = acc[h + 2] * dn, p3 = acc[h + 3] * dn;
        *(float4*)(o + h) = make_float4(p0, p1, p2, p3);
        *(float4*)(q + h) = make_float4(p0 * dn + bsh[h], p1 * dn + bsh[h + 1],
                                        p2 * dn + bsh[h + 2], p3 * dn + bsh[h + 3]);
    }
}

// ---------- 9/11. chunked aggregation: pass-major blocks; Q[n][h] += dis[n]*sum P[src][h] ----------
__global__ __launch_bounds__(256) void k_aggP(const float* __restrict__ P, const unsigned int* __restrict__ csr,
                                              const int* __restrict__ NCO, const float* __restrict__ dis,
                                              float* __restrict__ Q) {
    int pass = blockIdx.x / NPB, rb = blockIdx.x % NPB;
    int t = rb * 256 + threadIdx.x;
    int n = t >> 4, h = t & 15;                 // NPB*256/16 == N_ exactly
    const int* nco = NCO + (size_t)pass * N1;
    int s = nco[n], e = nco[n + 1];
    if (s >= e) return;
    float a0 = 0.f, a1 = 0.f, a2 = 0.f, a3 = 0.f;
    int p = s;
    for (; p + 4 <= e; p += 4) {
        unsigned int r0 = csr[p], r1 = csr[p + 1], r2 = csr[p + 2], r3 = csr[p + 3];
        a0 += P[r0 * 16 + h]; a1 += P[r1 * 16 + h];
        a2 += P[r2 * 16 + h]; a3 += P[r3 * 16 + h];
    }
    for (; p < e; ++p) a0 += P[csr[p] * 16 + h];
    atomicAdd(&Q[(size_t)n * 16 + h], dis[n] * ((a0 + a1) + (a2 + a3)));
}

// ---------- 12. pool + fc ----------
__global__ __launch_bounds__(256) void k_pool_fc(const float* __restrict__ h2, const int* __restrict__ batch,
                                                 const float* __restrict__ Wfc, const float* __restrict__ bfc,
                                                 float* __restrict__ out) {
    int b = blockIdx.x;
    int lo = 0, hi = N_;
    while (lo < hi) { int m = (lo + hi) >> 1; if (batch[m] < b) lo = m + 1; else hi = m; }
    int start = lo;
    lo = start; hi = N_;
    while (lo < hi) { int m = (lo + hi) >> 1; if (batch[m] < b + 1) lo = m + 1; else hi = m; }
    int end = lo;

    int t = threadIdx.x;
    int h = t & 15, q = t >> 4;
    float acc = 0.f;
    for (int n = start + q; n < end; n += 16) acc += h2[(size_t)n * H_ + h];
    acc += __shfl_xor(acc, 16);
    acc += __shfl_xor(acc, 32);

    __shared__ float part[4][H_];
    __shared__ float pooled[H_];
    if ((t & 63) < 16) part[t >> 6][h] = acc;
    __syncthreads();
    if (t < H_) {
        float s2 = part[0][t] + part[1][t] + part[2][t] + part[3][t];
        pooled[t] = s2 / fmaxf((float)(end - start), 1.0f);
    }
    __syncthreads();
    if (t < C_) {
        float o = bfc[t];
#pragma unroll
        for (int hh = 0; hh < H_; ++hh) o += pooled[hh] * Wfc[hh * C_ + t];
        out[b * C_ + t] = o;
    }
}

extern "C" void kernel_launch(void* const* d_in, const int* in_sizes, int n_in,
                              void* d_out, int out_size, void* d_ws, size_t ws_size,
                              hipStream_t stream) {
    const float* x    = (const float*)d_in[0];
    const int*   ei   = (const int*)d_in[1];
    const int*   batch= (const int*)d_in[2];
    const float* W1   = (const float*)d_in[3];
    const float* b1   = (const float*)d_in[4];
    const float* W2   = (const float*)d_in[5];
    const float* b2   = (const float*)d_in[6];
    const float* Wfc  = (const float*)d_in[7];
    const float* bfc  = (const float*)d_in[8];
    float* out = (float*)d_out;

    const int* row = ei;          // sources
    const int* col = ei + E_;     // destinations

    size_t off = 0;
    auto alloc = [&](size_t bytes) -> void* {
        void* p = (char*)d_ws + off;
        off += (bytes + 255) & ~(size_t)255;
        return p;
    };
    // cnt_mat (NKEY*NT ints = 5.47MB) dead after k_part; NCO (7*(N+1) ints = 5.6MB) written in k_part2.
    size_t unionBytes = (size_t)NCH * N1 * 4;                       // 5.6MB >= cnt_mat 5.474MB
    char*         ubase       = (char*)alloc(unionBytes);
    int*          cnt_mat     = (int*)ubase;
    int*          NCO         = (int*)ubase;
    int*          keyTotal    = (int*)alloc((size_t)NKEY * 4);
    int*          keyStart    = (int*)alloc((size_t)(NKEY + 1) * 4);
    unsigned int* edges_part  = (unsigned int*)alloc((size_t)E_ * 4);    // 25.6MB
    float*        dis         = (float*)alloc((size_t)N_ * 4);           // 0.8MB
    float*        P           = (float*)alloc((size_t)N_ * H_ * 4);      // 12.8MB
    float*        Q           = (float*)alloc((size_t)N_ * H_ * 4);      // 12.8MB (contiguous after P)
    unsigned int* spill       = (unsigned int*)P;                        // P∪Q = 6.4M uints, free at part2 time
    (void)ws_size; (void)in_sizes; (void)n_in; (void)out_size;

    const int gridN = (N_ + 255) / 256;

    k_count   <<<NT, 256, 0, stream>>>(row, col, cnt_mat);
    k_scan_col<<<NKEY, 256, 0, stream>>>(cnt_mat, keyTotal);
    k_scan_top<<<1, 1024, 0, stream>>>(keyTotal, keyStart);
    k_part    <<<NT, 256, 0, stream>>>(row, col, cnt_mat, keyStart, edges_part);
    k_part2   <<<NKEY, 256, 0, stream>>>(edges_part, keyStart, NCO, spill);
    k_sent    <<<1, 32, 0, stream>>>(keyStart, NCO);
    k_disNCO  <<<gridN, 256, 0, stream>>>(NCO, dis);

    // conv1
    k_gemm1s<<<gridN, 256, 0, stream>>>(x, W1, dis, b1, P, Q);
    k_aggP  <<<NCH * NPB, 256, 0, stream>>>(P, edges_part, NCO, dis, Q);
    // conv2 (relu fused into gemm2 input; in-place Q read/write is thread-local)
    k_gemm2s<<<gridN, 256, 0, stream>>>(Q, W2, dis, b2, P, Q);
    k_aggP  <<<NCH * NPB, 256, 0, stream>>>(P, edges_part, NCO, dis, Q);

    k_pool_fc<<<B_, 256, 0, stream>>>(Q, batch, Wfc, bfc, out);
}

// Round 6
// 409.367 us; speedup vs baseline: 3.8946x; 1.4218x over previous
//
#include <hip/hip_runtime.h>

#define N_ 200000
#define E_ 6400000
#define F_ 128
#define H_ 16
#define C_ 10
#define B_ 512

#define BSH   8                      // dst bucket = dst>>8  (256 nodes)
#define NBUCK 782                    // ceil(N/256)
#define NT    250                    // partition tiles
#define EPT   25600                  // edges per tile (NT*EPT == E_)
#define N1    (N_ + 1)
#define STG   12288                  // part2 LDS staging cap (mean 8192, std ~90)
#define AGGB  3125                   // N_*4/256

// ---------- 1. per-tile bucket histogram (dst only) ----------
__global__ __launch_bounds__(256) void k_count(const int* __restrict__ col, int* __restrict__ cnt_mat) {
    __shared__ int hist[NBUCK];
    int tid = threadIdx.x, tile = blockIdx.x;
    for (int i = tid; i < NBUCK; i += 256) hist[i] = 0;
    __syncthreads();
    const int* c = col + (size_t)tile * EPT;
    for (int i = tid; i < EPT; i += 256) atomicAdd(&hist[c[i] >> BSH], 1);
    __syncthreads();
    for (int i = tid; i < NBUCK; i += 256) cnt_mat[(size_t)i * NT + tile] = hist[i];   // bucket-major
}

// ---------- 2. per-bucket scan over tiles (exclusive, in place) + totals ----------
__global__ __launch_bounds__(256) void k_scan_col(int* __restrict__ cnt_mat, int* __restrict__ keyTotal) {
    __shared__ int s[256];
    int k = blockIdx.x, t = threadIdx.x;
    int v = (t < NT) ? cnt_mat[(size_t)k * NT + t] : 0;
    s[t] = v;
    __syncthreads();
    for (int off = 1; off < 256; off <<= 1) {
        int tmp = (t >= off) ? s[t - off] : 0;
        __syncthreads();
        s[t] += tmp;
        __syncthreads();
    }
    if (t == 255) keyTotal[k] = s[255];
    if (t < NT) cnt_mat[(size_t)k * NT + t] = s[t] - v;
}

// ---------- 3. scan bucket totals -> keyStart[NBUCK+1] ----------
__global__ __launch_bounds__(1024) void k_scan_top(const int* __restrict__ keyTotal, int* __restrict__ keyStart) {
    __shared__ int s[1024];
    int t = threadIdx.x;
    int v = (t < NBUCK) ? keyTotal[t] : 0;
    s[t] = v;
    __syncthreads();
    for (int off = 1; off < 1024; off <<= 1) {
        int tmp = (t >= off) ? s[t - off] : 0;
        __syncthreads();
        s[t] += tmp;
        __syncthreads();
    }
    if (t < NBUCK) keyStart[t] = s[t] - v;
    if (t == NBUCK - 1) keyStart[NBUCK] = s[t];   // == E_
}

// ---------- 4. partition edges by bucket (packed: src | dst_local<<24) ----------
__global__ __launch_bounds__(256) void k_part(const int* __restrict__ row, const int* __restrict__ col,
                                              const int* __restrict__ cnt_mat, const int* __restrict__ keyStart,
                                              unsigned int* __restrict__ edges_part) {
    __shared__ int cur[NBUCK];
    int tid = threadIdx.x, tile = blockIdx.x;
    for (int i = tid; i < NBUCK; i += 256) cur[i] = cnt_mat[(size_t)i * NT + tile] + keyStart[i];
    __syncthreads();
    const int* r = row + (size_t)tile * EPT;
    const int* c = col + (size_t)tile * EPT;
    for (int i = tid; i < EPT; i += 256) {
        int src = r[i], dst = c[i];
        int p = atomicAdd(&cur[dst >> BSH], 1);
        edges_part[p] = (unsigned int)src | ((unsigned int)(dst & 255) << 24);
    }
}

// ---------- 5. in-bucket counting sort by dst_local; writes CO, dis; strips to src ----------
__global__ __launch_bounds__(256) void k_part2(unsigned int* __restrict__ edges_part, const int* __restrict__ keyStart,
                                               int* __restrict__ CO, float* __restrict__ dis,
                                               unsigned int* __restrict__ spill) {
    __shared__ unsigned int stg[STG];    // 48 KB
    __shared__ int cnt[256];
    __shared__ int scn[256];
    __shared__ int cur[256];
    int b = blockIdx.x, tid = threadIdx.x;
    int s = keyStart[b], e = keyStart[b + 1], len = e - s;
    cnt[tid] = 0;
    __syncthreads();
    bool small = (len <= STG);
    if (small) {
        for (int i = tid; i < len; i += 256) {
            unsigned int w = edges_part[s + i];
            stg[i] = w;
            atomicAdd(&cnt[w >> 24], 1);
        }
    } else {   // statistically unreachable; correct fallback via spill (P/Q region, unused yet)
        for (int i = tid; i < len; i += 256) {
            unsigned int w = edges_part[s + i];
            spill[s + i] = w;
            atomicAdd(&cnt[w >> 24], 1);
        }
    }
    __syncthreads();
    int v = cnt[tid];
    scn[tid] = v;
    __syncthreads();
    for (int off = 1; off < 256; off <<= 1) {
        int tmp = (tid >= off) ? scn[tid - off] : 0;
        __syncthreads();
        scn[tid] += tmp;
        __syncthreads();
    }
    int excl = scn[tid] - v;
    cur[tid] = excl;
    int n = (b << BSH) + tid;
    if (n < N_) {
        CO[n] = s + excl;
        dis[n] = rsqrtf(1.0f + (float)v);
    }
    if (b == 0 && tid == 0) CO[N_] = E_;
    __syncthreads();
    if (small) {
        for (int i = tid; i < len; i += 256) {
            unsigned int w = stg[i];
            int pos = atomicAdd(&cur[w >> 24], 1);
            edges_part[s + pos] = w & 0xFFFFFFu;
        }
    } else {
        for (int i = tid; i < len; i += 256) {
            unsigned int w = spill[s + i];
            int pos = atomicAdd(&cur[w >> 24], 1);
            edges_part[s + pos] = w & 0xFFFFFFu;
        }
    }
}

// ---------- 6. GEMM1: P = dis*(x@W1) ----------
__global__ __launch_bounds__(256) void k_gemm1s(const float* __restrict__ x, const float* __restrict__ W1,
                                                const float* __restrict__ dis, float* __restrict__ P) {
    __shared__ float w[F_ * H_];
    for (int i = threadIdx.x; i < F_ * H_; i += 256) w[i] = W1[i];
    __syncthreads();
    int n = blockIdx.x * 256 + threadIdx.x;
    if (n >= N_) return;
    float acc[H_];
#pragma unroll
    for (int h = 0; h < H_; ++h) acc[h] = 0.f;
    const float4* xr = reinterpret_cast<const float4*>(x + (size_t)n * F_);
#pragma unroll 4
    for (int k4 = 0; k4 < F_ / 4; ++k4) {
        float4 xv = xr[k4];
        int k = k4 * 4;
#pragma unroll
        for (int h = 0; h < H_; ++h) {
            acc[h] += xv.x * w[(k + 0) * H_ + h] + xv.y * w[(k + 1) * H_ + h]
                    + xv.z * w[(k + 2) * H_ + h] + xv.w * w[(k + 3) * H_ + h];
        }
    }
    float dn = dis[n];
    float* o = P + (size_t)n * H_;
#pragma unroll
    for (int h = 0; h < H_; h += 4)
        *(float4*)(o + h) = make_float4(acc[h] * dn, acc[h + 1] * dn, acc[h + 2] * dn, acc[h + 3] * dn);
}

// ---------- 8. GEMM2: P = dis*(hin@W2)  (hin already ReLU'd) ----------
__global__ __launch_bounds__(256) void k_gemm2s(const float* __restrict__ hin, const float* __restrict__ W2,
                                                const float* __restrict__ dis, float* __restrict__ P) {
    __shared__ float w[H_ * H_];
    if (threadIdx.x < H_ * H_) w[threadIdx.x] = W2[threadIdx.x];
    __syncthreads();
    int n = blockIdx.x * 256 + threadIdx.x;
    if (n >= N_) return;
    float hv[H_];
    const float4* hr = reinterpret_cast<const float4*>(hin + (size_t)n * H_);
#pragma unroll
    for (int q = 0; q < 4; ++q) {
        float4 v = hr[q];
        hv[q * 4 + 0] = v.x; hv[q * 4 + 1] = v.y; hv[q * 4 + 2] = v.z; hv[q * 4 + 3] = v.w;
    }
    float acc[H_];
#pragma unroll
    for (int h = 0; h < H_; ++h) acc[h] = 0.f;
#pragma unroll
    for (int k = 0; k < H_; ++k)
#pragma unroll
        for (int h = 0; h < H_; ++h) acc[h] += hv[k] * w[k * H_ + h];
    float dn = dis[n];
    float* o = P + (size_t)n * H_;
#pragma unroll
    for (int h = 0; h < H_; h += 4)
        *(float4*)(o + h) = make_float4(acc[h] * dn, acc[h + 1] * dn, acc[h + 2] * dn, acc[h + 3] * dn);
}

// ---------- 7/9. CSR aggregation: thread = (node, h-quad); register acc; single store ----------
// Q[n][hq] = dis[n] * (sum_{edges->n} P[src][hq] + P[n][hq]) + bias[hq]   (+relu)
template <int RELU>
__global__ __launch_bounds__(256) void k_agg(const float4* __restrict__ P4, const unsigned int* __restrict__ csr,
                                             const int* __restrict__ CO, const float* __restrict__ dis,
                                             const float* __restrict__ bias, float4* __restrict__ Q4) {
    int t = blockIdx.x * 256 + threadIdx.x;      // AGGB*256 == N_*4 exactly
    int n = t >> 2, hq = t & 3;
    int s = CO[n], e = CO[n + 1];
    float4 a0 = {0, 0, 0, 0}, a1 = {0, 0, 0, 0}, a2 = {0, 0, 0, 0}, a3 = {0, 0, 0, 0};
    float4 a4 = {0, 0, 0, 0}, a5 = {0, 0, 0, 0}, a6 = {0, 0, 0, 0}, a7 = {0, 0, 0, 0};
    int p = s;
    for (; p + 8 <= e; p += 8) {
        unsigned int r0 = csr[p    ], r1 = csr[p + 1], r2 = csr[p + 2], r3 = csr[p + 3];
        unsigned int r4 = csr[p + 4], r5 = csr[p + 5], r6 = csr[p + 6], r7 = csr[p + 7];
        float4 v0 = P4[(size_t)r0 * 4 + hq], v1 = P4[(size_t)r1 * 4 + hq];
        float4 v2 = P4[(size_t)r2 * 4 + hq], v3 = P4[(size_t)r3 * 4 + hq];
        float4 v4 = P4[(size_t)r4 * 4 + hq], v5 = P4[(size_t)r5 * 4 + hq];
        float4 v6 = P4[(size_t)r6 * 4 + hq], v7 = P4[(size_t)r7 * 4 + hq];
        a0.x += v0.x; a0.y += v0.y; a0.z += v0.z; a0.w += v0.w;
        a1.x += v1.x; a1.y += v1.y; a1.z += v1.z; a1.w += v1.w;
        a2.x += v2.x; a2.y += v2.y; a2.z += v2.z; a2.w += v2.w;
        a3.x += v3.x; a3.y += v3.y; a3.z += v3.z; a3.w += v3.w;
        a4.x += v4.x; a4.y += v4.y; a4.z += v4.z; a4.w += v4.w;
        a5.x += v5.x; a5.y += v5.y; a5.z += v5.z; a5.w += v5.w;
        a6.x += v6.x; a6.y += v6.y; a6.z += v6.z; a6.w += v6.w;
        a7.x += v7.x; a7.y += v7.y; a7.z += v7.z; a7.w += v7.w;
    }
    for (; p < e; ++p) {
        float4 v = P4[(size_t)csr[p] * 4 + hq];
        a0.x += v.x; a0.y += v.y; a0.z += v.z; a0.w += v.w;
    }
    float4 sum;
    sum.x = ((a0.x + a1.x) + (a2.x + a3.x)) + ((a4.x + a5.x) + (a6.x + a7.x));
    sum.y = ((a0.y + a1.y) + (a2.y + a3.y)) + ((a4.y + a5.y) + (a6.y + a7.y));
    sum.z = ((a0.z + a1.z) + (a2.z + a3.z)) + ((a4.z + a5.z) + (a6.z + a7.z));
    sum.w = ((a0.w + a1.w) + (a2.w + a3.w)) + ((a4.w + a5.w) + (a6.w + a7.w));
    float4 ps = P4[(size_t)n * 4 + hq];
    float4 b4 = ((const float4*)bias)[hq];
    float dn = dis[n];
    float4 v;
    v.x = dn * (sum.x + ps.x) + b4.x;
    v.y = dn * (sum.y + ps.y) + b4.y;
    v.z = dn * (sum.z + ps.z) + b4.z;
    v.w = dn * (sum.w + ps.w) + b4.w;
    if (RELU) {
        v.x = fmaxf(v.x, 0.f); v.y = fmaxf(v.y, 0.f);
        v.z = fmaxf(v.z, 0.f); v.w = fmaxf(v.w, 0.f);
    }
    Q4[(size_t)n * 4 + hq] = v;
}

// ---------- 10. pool + fc ----------
__global__ __launch_bounds__(256) void k_pool_fc(const float* __restrict__ h2, const int* __restrict__ batch,
                                                 const float* __restrict__ Wfc, const float* __restrict__ bfc,
                                                 float* __restrict__ out) {
    int b = blockIdx.x;
    int lo = 0, hi = N_;
    while (lo < hi) { int m = (lo + hi) >> 1; if (batch[m] < b) lo = m + 1; else hi = m; }
    int start = lo;
    lo = start; hi = N_;
    while (lo < hi) { int m = (lo + hi) >> 1; if (batch[m] < b + 1) lo = m + 1; else hi = m; }
    int end = lo;

    int t = threadIdx.x;
    int h = t & 15, q = t >> 4;
    float acc = 0.f;
    for (int n = start + q; n < end; n += 16) acc += h2[(size_t)n * H_ + h];
    acc += __shfl_xor(acc, 16);
    acc += __shfl_xor(acc, 32);

    __shared__ float part[4][H_];
    __shared__ float pooled[H_];
    if ((t & 63) < 16) part[t >> 6][h] = acc;
    __syncthreads();
    if (t < H_) {
        float s2 = part[0][t] + part[1][t] + part[2][t] + part[3][t];
        pooled[t] = s2 / fmaxf((float)(end - start), 1.0f);
    }
    __syncthreads();
    if (t < C_) {
        float o = bfc[t];
#pragma unroll
        for (int hh = 0; hh < H_; ++hh) o += pooled[hh] * Wfc[hh * C_ + t];
        out[b * C_ + t] = o;
    }
}

extern "C" void kernel_launch(void* const* d_in, const int* in_sizes, int n_in,
                              void* d_out, int out_size, void* d_ws, size_t ws_size,
                              hipStream_t stream) {
    const float* x    = (const float*)d_in[0];
    const int*   ei   = (const int*)d_in[1];
    const int*   batch= (const int*)d_in[2];
    const float* W1   = (const float*)d_in[3];
    const float* b1   = (const float*)d_in[4];
    const float* W2   = (const float*)d_in[5];
    const float* b2   = (const float*)d_in[6];
    const float* Wfc  = (const float*)d_in[7];
    const float* bfc  = (const float*)d_in[8];
    float* out = (float*)d_out;

    const int* row = ei;          // sources
    const int* col = ei + E_;     // destinations

    size_t off = 0;
    auto alloc = [&](size_t bytes) -> void* {
        void* p = (char*)d_ws + off;
        off += (bytes + 255) & ~(size_t)255;
        return p;
    };
    int*          cnt_mat     = (int*)alloc((size_t)NBUCK * NT * 4);     // 0.78 MB
    int*          keyTotal    = (int*)alloc((size_t)NBUCK * 4);
    int*          keyStart    = (int*)alloc((size_t)(NBUCK + 1) * 4);
    unsigned int* edges_part  = (unsigned int*)alloc((size_t)E_ * 4);    // 25.6 MB
    int*          CO          = (int*)alloc((size_t)N1 * 4);             // 0.8 MB
    float*        dis         = (float*)alloc((size_t)N_ * 4);           // 0.8 MB
    float*        P           = (float*)alloc((size_t)N_ * H_ * 4);      // 12.8 MB
    float*        Q           = (float*)alloc((size_t)N_ * H_ * 4);      // 12.8 MB (contiguous after P)
    unsigned int* spill       = (unsigned int*)P;                        // P∪Q = E_ words, free at part2 time
    (void)ws_size; (void)in_sizes; (void)n_in; (void)out_size;

    const int gridN = (N_ + 255) / 256;

    k_count   <<<NT, 256, 0, stream>>>(col, cnt_mat);
    k_scan_col<<<NBUCK, 256, 0, stream>>>(cnt_mat, keyTotal);
    k_scan_top<<<1, 1024, 0, stream>>>(keyTotal, keyStart);
    k_part    <<<NT, 256, 0, stream>>>(row, col, cnt_mat, keyStart, edges_part);
    k_part2   <<<NBUCK, 256, 0, stream>>>(edges_part, keyStart, CO, dis, spill);

    // conv1
    k_gemm1s<<<gridN, 256, 0, stream>>>(x, W1, dis, P);
    k_agg<1><<<AGGB, 256, 0, stream>>>((const float4*)P, edges_part, CO, dis, b1, (float4*)Q);
    // conv2
    k_gemm2s<<<gridN, 256, 0, stream>>>(Q, W2, dis, P);
    k_agg<0><<<AGGB, 256, 0, stream>>>((const float4*)P, edges_part, CO, dis, b2, (float4*)Q);

    k_pool_fc<<<B_, 256, 0, stream>>>(Q, batch, Wfc, bfc, out);
}